// Round 5
// baseline (1761.699 us; speedup 1.0000x reference)
//
#include <hip/hip_runtime.h>
#include <math.h>

// Problem constants
#define NTOT 32768   // T*B
#define CIN  201
#define S    67      // keypoints (seq len)
#define E    8
#define H    2
#define L    12
#define FF   16
#define OUTC 128
#define KF   536     // S*E
#define EPB  15      // elements per block (15*67 = 1005 of 1024 lanes = 98.1% fill)
#define THREADS 1024
#define NPAIR 34     // t-pair slots 0..33; slot 33 = {t=66 real, t=67 zero-pad}

typedef float v2f __attribute__((ext_vector_type(2)));

#if __has_builtin(__builtin_amdgcn_exp2f)
#define EXP2F(x) __builtin_amdgcn_exp2f(x)
#else
#define EXP2F(x) exp2f(x)
#endif
#if __has_builtin(__builtin_amdgcn_rcpf)
#define RCPF(x) __builtin_amdgcn_rcpf(x)
#else
#define RCPF(x) (1.0f/(x))
#endif
#if __has_builtin(__builtin_amdgcn_rsqf)
#define RSQF(x) __builtin_amdgcn_rsqf(x)
#else
#define RSQF(x) rsqrtf(x)
#endif

// 0.5 (=1/sqrt(DH)) * log2(e)
#define QSCALE 0.7213475204444817f

__device__ __forceinline__ void layernorm8(float* xr, const float* __restrict__ gg,
                                           const float* __restrict__ bb) {
    float m = 0.f;
    #pragma unroll
    for (int e = 0; e < E; ++e) m += xr[e];
    m *= 0.125f;
    float v = 0.f;
    #pragma unroll
    for (int e = 0; e < E; ++e) { float d = xr[e] - m; v += d * d; }
    v *= 0.125f;
    float rs = RSQF(v + 1e-5f);
    #pragma unroll
    for (int e = 0; e < E; ++e) xr[e] = (xr[e] - m) * rs * gg[e] + bb[e];
}

// Pack per-layer transposed weights into wp[L][512]:
//   [0:192)   qkvt[e][j]  = ipw[l][j][e]   (e<8, j<24)
//   [192:256) aowt[e2][e] = aow[l][e][e2]
//   [256:384) f1t[e][f]   = f1w[l][f][e]   (f<16)
//   [384:512) f2t[f][e]   = f2w[l][e][f]
__global__ void prep_kernel(const float* __restrict__ ipw, const float* __restrict__ aow,
                            const float* __restrict__ f1w, const float* __restrict__ f2w,
                            float* __restrict__ wp)
{
    int idx = blockIdx.x * 256 + threadIdx.x;
    if (idx >= L * 512) return;
    int l = idx >> 9, r = idx & 511;
    float v;
    if (r < 192)      { int e = r / 24, j = r % 24;          v = ipw[l*192 + j*8 + e]; }
    else if (r < 256) { int q = r - 192; int e2 = q / 8, e = q % 8; v = aow[l*64 + e*8 + e2]; }
    else if (r < 384) { int q = r - 256; int e = q / 16, f = q % 16; v = f1w[l*128 + f*8 + e]; }
    else              { int q = r - 384; int f = q / 8,  e = q % 8;  v = f2w[l*128 + e*16 + f]; }
    wp[idx] = v;
}

__global__ __launch_bounds__(THREADS, 8)
void enc_kernel(const float* __restrict__ pose,
                const float* __restrict__ ew,  const float* __restrict__ ebias,
                const float* __restrict__ wp,  const float* __restrict__ ipb,
                const float* __restrict__ aob,
                const float* __restrict__ f1b, const float* __restrict__ f2b,
                const float* __restrict__ g1,  const float* __restrict__ b1,
                const float* __restrict__ g2,  const float* __restrict__ b2,
                float* __restrict__ xf)
{
    // t-pair interleaved K/V: buf[0]=KA {kx_t,kx_t1,ky_t,ky_t1}, buf[1]=KB {kz..kw..},
    // buf[2]=VA, buf[3]=VB.  4*30*34*16 = 65280 B (fits 64 KiB; 2 blocks/CU)
    __shared__ float4 buf[4][EPB * H][NPAIR];

    const int lid = threadIdx.x;
    const int g   = lid / S;            // element in block (0..14 valid)
    const int s   = lid - g * S;        // keypoint row
    const int n   = blockIdx.x * EPB + g;
    const bool active = (g < EPB) && (n < NTOT);
    const int ii = s >> 1, hf = s & 1;

    // ---- embed ----
    float xr[E];
    if (active) {
        const float* p = pose + (size_t)n * CIN + 3 * s;
        float r0 = p[0], r1 = p[1], r2 = p[2];
        #pragma unroll
        for (int e = 0; e < E; ++e)
            xr[e] = ebias[e] + r0 * ew[e*3+0] + r1 * ew[e*3+1] + r2 * ew[e*3+2];
    }

    #pragma unroll 1
    for (int l = 0; l < L; ++l) {
        const float* WL   = wp + l * 512;
        const float* qkvt = WL;          // [e][24]
        const float* aowt = WL + 192;    // [e2][8]
        const float* f1t  = WL + 256;    // [e][16]
        const float* f2t  = WL + 384;    // [f][8]
        const float* bq   = ipb + l * 24;

        float qsc[E];
        if (active) {
            v2f xs[E];
            #pragma unroll
            for (int e = 0; e < E; ++e) xs[e] = (v2f){xr[e], xr[e]};

            v2f qkv[12];
            #pragma unroll
            for (int p = 0; p < 12; ++p) {
                v2f a = *(const v2f*)(bq + 2*p);
                #pragma unroll
                for (int e = 0; e < E; ++e)
                    a += xs[e] * (*(const v2f*)(qkvt + e*24 + 2*p));
                qkv[p] = a;
            }
            #pragma unroll
            for (int p = 0; p < 4; ++p) {
                qsc[2*p]   = qkv[p].x * QSCALE;
                qsc[2*p+1] = qkv[p].y * QSCALE;
            }
            // scatter K/V into t-pair interleaved layout
            #pragma unroll
            for (int h = 0; h < H; ++h) {
                const int gh = g*2 + h;
                float* pKA = (float*)&buf[0][gh][ii];
                float* pKB = (float*)&buf[1][gh][ii];
                float* pVA = (float*)&buf[2][gh][ii];
                float* pVB = (float*)&buf[3][gh][ii];
                pKA[hf] = qkv[4+2*h].x;  pKA[2+hf] = qkv[4+2*h].y;
                pKB[hf] = qkv[5+2*h].x;  pKB[2+hf] = qkv[5+2*h].y;
                pVA[hf] = qkv[8+2*h].x;  pVA[2+hf] = qkv[8+2*h].y;
                pVB[hf] = qkv[9+2*h].x;  pVB[2+hf] = qkv[9+2*h].y;
                if (s == S - 1) {
                    // zero the t=67 pad halves (hf=1 of slot 33):
                    // k=0 -> exp2(0)=1, corrected by lsum-=1; v=0 -> no o contribution
                    pKA[1] = 0.f; pKA[3] = 0.f;
                    pKB[1] = 0.f; pKB[3] = 0.f;
                    pVA[1] = 0.f; pVA[3] = 0.f;
                    pVB[1] = 0.f; pVB[3] = 0.f;
                }
            }
        }
        __syncthreads();

        if (active) {
            float oo[E];
            #pragma unroll
            for (int h = 0; h < H; ++h) {
                const int gh = g*2 + h;
                const float4* KA = buf[0][gh];
                const float4* KB = buf[1][gh];
                const float4* VA = buf[2][gh];
                const float4* VB = buf[3][gh];
                const float q0s = qsc[4*h+0], q1s = qsc[4*h+1];
                const float q2s = qsc[4*h+2], q3s = qsc[4*h+3];
                const v2f qx2 = {q0s, q0s}, qy2 = {q1s, q1s};
                const v2f qz2 = {q2s, q2s}, qw2 = {q3s, q3s};
                v2f l2 = {0.f, 0.f};
                v2f ox = {0.f,0.f}, oy = {0.f,0.f}, oz = {0.f,0.f}, ow = {0.f,0.f};
                #pragma unroll
                for (int i = 0; i < NPAIR; ++i) {       // t = 0..67 (67 = zero-pad)
                    float4 ka = KA[i], kb = KB[i];
                    float4 va = VA[i], vb = VB[i];
                    v2f sc = qx2 * *(const v2f*)&ka.x + qy2 * *(const v2f*)&ka.z
                           + qz2 * *(const v2f*)&kb.x + qw2 * *(const v2f*)&kb.z;
                    v2f e2;
                    e2.x = EXP2F(sc.x);
                    e2.y = EXP2F(sc.y);
                    l2 += e2;
                    ox += e2 * *(const v2f*)&va.x;
                    oy += e2 * *(const v2f*)&va.z;
                    oz += e2 * *(const v2f*)&vb.x;
                    ow += e2 * *(const v2f*)&vb.z;
                }
                float lsum = l2.x + l2.y - 1.0f;   // remove pad's exp2(0)=1
                float inv  = RCPF(lsum);
                oo[4*h+0] = (ox.x + ox.y) * inv;
                oo[4*h+1] = (oy.x + oy.y) * inv;
                oo[4*h+2] = (oz.x + oz.y) * inv;
                oo[4*h+3] = (ow.x + ow.y) * inv;
            }

            // attn_out + residual + LN1 (packed over output-pairs)
            {
                const float* ba = aob + l*E;
                v2f os[E];
                #pragma unroll
                for (int e2 = 0; e2 < E; ++e2) os[e2] = (v2f){oo[e2], oo[e2]};
                #pragma unroll
                for (int p = 0; p < 4; ++p) {
                    v2f a = *(const v2f*)(ba + 2*p);
                    #pragma unroll
                    for (int e2 = 0; e2 < E; ++e2)
                        a += os[e2] * (*(const v2f*)(aowt + e2*8 + 2*p));
                    xr[2*p]   += a.x;
                    xr[2*p+1] += a.y;
                }
            }
            layernorm8(xr, g1 + l*E, b1 + l*E);

            // FF (packed)
            {
                const float* fb1 = f1b + l*FF;
                const float* fb2 = f2b + l*E;
                v2f xs[E];
                #pragma unroll
                for (int e = 0; e < E; ++e) xs[e] = (v2f){xr[e], xr[e]};
                v2f t1p[8];
                #pragma unroll
                for (int p = 0; p < 8; ++p) {
                    v2f a = *(const v2f*)(fb1 + 2*p);
                    #pragma unroll
                    for (int e = 0; e < E; ++e)
                        a += xs[e] * (*(const v2f*)(f1t + e*16 + 2*p));
                    a.x = fmaxf(a.x, 0.f);
                    a.y = fmaxf(a.y, 0.f);
                    t1p[p] = a;
                }
                v2f ts[FF];
                #pragma unroll
                for (int p = 0; p < 8; ++p) {
                    ts[2*p]   = (v2f){t1p[p].x, t1p[p].x};
                    ts[2*p+1] = (v2f){t1p[p].y, t1p[p].y};
                }
                #pragma unroll
                for (int p = 0; p < 4; ++p) {
                    v2f a = *(const v2f*)(fb2 + 2*p);
                    #pragma unroll
                    for (int f = 0; f < FF; ++f)
                        a += ts[f] * (*(const v2f*)(f2t + f*8 + 2*p));
                    xr[2*p]   += a.x;
                    xr[2*p+1] += a.y;
                }
            }
            layernorm8(xr, g2 + l*E, b2 + l*E);
        }
        __syncthreads();   // protect K/V before next layer overwrites
    }

    if (active) {
        float4* o4 = (float4*)(xf + (size_t)n * KF + s * E);
        o4[0] = make_float4(xr[0], xr[1], xr[2], xr[3]);
        o4[1] = make_float4(xr[4], xr[5], xr[6], xr[7]);
    }
}

// wt[k][c] = ow[c][k]
__global__ void tr_kernel(const float* __restrict__ ow, float* __restrict__ wt)
{
    int i = blockIdx.x * 256 + threadIdx.x;
    if (i < OUTC * KF) {
        int c = i / KF, k = i - c * KF;
        wt[k * OUTC + c] = ow[i];
    }
}

// out = tanh(Xf[32768,536] @ Wt[536,128] + b)
__global__ __launch_bounds__(256, 4)
void out_kernel(const float* __restrict__ xf, const float* __restrict__ wt,
                const float* __restrict__ ob, float* __restrict__ out)
{
    __shared__ float Xs[32][68];
    const int lid = threadIdx.x;
    const int tx  = lid & 31;
    const int ty  = lid >> 5;
    const int n0  = blockIdx.x * 32;

    float acc[4][4] = {};

    #pragma unroll 1
    for (int kc = 0; kc < 9; ++kc) {
        const int kb = kc * 64;
        const int kw = (kc < 8) ? 64 : 24;
        __syncthreads();
        const int nvec = 32 * (kw >> 2);
        for (int i = lid; i < nvec; i += 256) {
            int r = i / (kw >> 2), kq = i - r * (kw >> 2);
            *(float4*)&Xs[r][kq*4] =
                *(const float4*)&xf[(size_t)(n0 + r) * KF + kb + kq*4];
        }
        __syncthreads();
        #pragma unroll 4
        for (int k = 0; k < kw; ++k) {
            float4 w4 = *(const float4*)&wt[(size_t)(kb + k) * OUTC + tx*4];
            #pragma unroll
            for (int i = 0; i < 4; ++i) {
                float x = Xs[ty*4 + i][k];
                acc[i][0] += x*w4.x; acc[i][1] += x*w4.y;
                acc[i][2] += x*w4.z; acc[i][3] += x*w4.w;
            }
        }
    }

    const float4 bb = *(const float4*)&ob[tx*4];
    #pragma unroll
    for (int i = 0; i < 4; ++i) {
        int r = n0 + ty*4 + i;
        float4 v;
        v.x = tanhf(acc[i][0] + bb.x);
        v.y = tanhf(acc[i][1] + bb.y);
        v.z = tanhf(acc[i][2] + bb.z);
        v.w = tanhf(acc[i][3] + bb.w);
        *(float4*)(out + (size_t)r * OUTC + tx*4) = v;
    }
}

extern "C" void kernel_launch(void* const* d_in, const int* in_sizes, int n_in,
                              void* d_out, int out_size, void* d_ws, size_t ws_size,
                              hipStream_t stream) {
    (void)in_sizes; (void)n_in; (void)out_size; (void)ws_size;
    const float* pose = (const float*)d_in[0];
    const float* ew   = (const float*)d_in[1];
    const float* eb   = (const float*)d_in[2];
    const float* ipw  = (const float*)d_in[3];
    const float* ipb  = (const float*)d_in[4];
    const float* aow  = (const float*)d_in[5];
    const float* aob  = (const float*)d_in[6];
    const float* f1w  = (const float*)d_in[7];
    const float* f1b  = (const float*)d_in[8];
    const float* f2w  = (const float*)d_in[9];
    const float* f2b  = (const float*)d_in[10];
    const float* g1   = (const float*)d_in[11];
    const float* b1   = (const float*)d_in[12];
    const float* g2   = (const float*)d_in[13];
    const float* b2   = (const float*)d_in[14];
    const float* ow   = (const float*)d_in[15];
    const float* ob   = (const float*)d_in[16];

    float* xf = (float*)d_ws;                               // 70.25 MB
    float* wt = xf + (size_t)NTOT * KF;                     // 268 KB
    float* wp = wt + (size_t)KF * OUTC;                     // 24 KB

    prep_kernel<<<(L*512 + 255)/256, 256, 0, stream>>>(ipw, aow, f1w, f2w, wp);
    const int grid1 = (NTOT + EPB - 1) / EPB;               // 2185
    enc_kernel<<<grid1, THREADS, 0, stream>>>(pose, ew, eb, wp, ipb, aob,
                                              f1b, f2b, g1, b1, g2, b2, xf);
    tr_kernel<<<(OUTC*KF + 255)/256, 256, 0, stream>>>(ow, wt);
    out_kernel<<<NTOT / 32, 256, 0, stream>>>(xf, wt, ob, (float*)d_out);
}

// Round 6
// 1324.023 us; speedup vs baseline: 1.3306x; 1.3306x over previous
//
#include <hip/hip_runtime.h>
#include <math.h>

// Problem constants
#define NTOT 32768   // T*B
#define CIN  201
#define S    67      // keypoints (seq len)
#define E    8
#define H    2
#define L    12
#define FF   16
#define OUTC 128
#define KF   536     // S*E
#define EPB  7       // elements per block
#define LPE  34      // lanes per element; lane j owns rows 2j, 2j+1 (row 67 = pad)
#define THREADS 256  // 7*34 = 238 active (93%)
#define NPAIR 34     // t-pair slots; slot 33 = {t=66 real, t=67 zero-pad}

typedef float v2f __attribute__((ext_vector_type(2)));

#if __has_builtin(__builtin_amdgcn_exp2f)
#define EXP2F(x) __builtin_amdgcn_exp2f(x)
#else
#define EXP2F(x) exp2f(x)
#endif
#if __has_builtin(__builtin_amdgcn_rcpf)
#define RCPF(x) __builtin_amdgcn_rcpf(x)
#else
#define RCPF(x) (1.0f/(x))
#endif
#if __has_builtin(__builtin_amdgcn_rsqf)
#define RSQF(x) __builtin_amdgcn_rsqf(x)
#else
#define RSQF(x) rsqrtf(x)
#endif

// 0.5 (=1/sqrt(DH)) * log2(e)
#define QSCALE 0.7213475204444817f

__device__ __forceinline__ v2f sp(float x) { return (v2f){x, x}; }

__device__ __forceinline__ void ln8p(v2f* x, const float* __restrict__ gg,
                                     const float* __restrict__ bb) {
    v2f m = {0.f, 0.f};
    #pragma unroll
    for (int e = 0; e < E; ++e) m += x[e];
    m *= 0.125f;
    v2f v = {0.f, 0.f};
    #pragma unroll
    for (int e = 0; e < E; ++e) { v2f d = x[e] - m; v += d * d; }
    v *= 0.125f;
    v2f rs;
    rs.x = RSQF(v.x + 1e-5f);
    rs.y = RSQF(v.y + 1e-5f);
    #pragma unroll
    for (int e = 0; e < E; ++e) x[e] = (x[e] - m) * rs * sp(gg[e]) + sp(bb[e]);
}

__global__ __launch_bounds__(THREADS, 5)
void enc_kernel(const float* __restrict__ pose,
                const float* __restrict__ ew,  const float* __restrict__ ebias,
                const float* __restrict__ ipw, const float* __restrict__ ipb,
                const float* __restrict__ aow, const float* __restrict__ aob,
                const float* __restrict__ f1w, const float* __restrict__ f1b,
                const float* __restrict__ f2w, const float* __restrict__ f2b,
                const float* __restrict__ g1,  const float* __restrict__ b1,
                const float* __restrict__ g2,  const float* __restrict__ b2,
                float* __restrict__ xf)
{
    // t-pair interleaved K/V; slot i holds t-pair {2i, 2i+1}.
    // KA={kx_t0,kx_t1,ky_t0,ky_t1}, KB={kz..,kw..}; VA/VB same for v.
    // 4 * 14 * 34 * 16 B = 30464 B -> 5 blocks/CU.
    __shared__ float4 KA[EPB * H][NPAIR];
    __shared__ float4 KB[EPB * H][NPAIR];
    __shared__ float4 VA[EPB * H][NPAIR];
    __shared__ float4 VB[EPB * H][NPAIR];

    const int lid = threadIdx.x;
    const int g   = lid / LPE;          // element in block (0..6 valid)
    const int j   = lid - g * LPE;      // pair index (0..33)
    const int n   = blockIdx.x * EPB + g;
    const bool active = (g < EPB) && (n < NTOT);
    const bool pad = (j == LPE - 1);    // lane 33: r1 = row 67 (doesn't exist)
    const int r0 = 2 * j;

    // ---- embed (rows r0=2j, r1=2j+1 packed into halves) ----
    v2f xr[E];
    if (active) {
        const float* p0 = pose + (size_t)n * CIN + 3 * r0;
        const float* p1 = pad ? p0 : (p0 + 3);
        v2f c0 = {p0[0], p1[0]};
        v2f c1 = {p0[1], p1[1]};
        v2f c2 = {p0[2], p1[2]};
        #pragma unroll
        for (int e = 0; e < E; ++e)
            xr[e] = sp(ebias[e]) + c0 * sp(ew[e*3+0]) + c1 * sp(ew[e*3+1])
                                 + c2 * sp(ew[e*3+2]);
    }

    #pragma unroll 1
    for (int l = 0; l < L; ++l) {
        const float* W  = ipw + l * 192;   // [24][8] row-major, wave-uniform
        const float* Bq = ipb + l * 24;

        v2f qp[E];
        if (active) {
            v2f qkv[24];
            #pragma unroll
            for (int jo = 0; jo < 24; ++jo) {
                v2f a = sp(Bq[jo]);
                #pragma unroll
                for (int e = 0; e < E; ++e) a += xr[e] * sp(W[jo*8 + e]);
                qkv[jo] = a;
            }
            #pragma unroll
            for (int c = 0; c < E; ++c) qp[c] = qkv[c] * QSCALE;
            if (pad) {   // row 67: k=0 (exp2(0)=1, fixed by lsum-1), v=0
                #pragma unroll
                for (int c = 8; c < 24; ++c) qkv[c].y = 0.f;
            }
            #pragma unroll
            for (int h = 0; h < H; ++h) {
                const int gh = g*2 + h;
                KA[gh][j] = make_float4(qkv[8+4*h+0].x, qkv[8+4*h+0].y,
                                        qkv[8+4*h+1].x, qkv[8+4*h+1].y);
                KB[gh][j] = make_float4(qkv[8+4*h+2].x, qkv[8+4*h+2].y,
                                        qkv[8+4*h+3].x, qkv[8+4*h+3].y);
                VA[gh][j] = make_float4(qkv[16+4*h+0].x, qkv[16+4*h+0].y,
                                        qkv[16+4*h+1].x, qkv[16+4*h+1].y);
                VB[gh][j] = make_float4(qkv[16+4*h+2].x, qkv[16+4*h+2].y,
                                        qkv[16+4*h+3].x, qkv[16+4*h+3].y);
            }
        }
        __syncthreads();

        if (active) {
            v2f os[E];   // os[e] = {o[r0][e], o[r1][e]}
            #pragma unroll
            for (int h = 0; h < H; ++h) {
                const int gh = g*2 + h;
                const float4* pKA = KA[gh];
                const float4* pKB = KB[gh];
                const float4* pVA = VA[gh];
                const float4* pVB = VB[gh];
                // row-specific q splats (low/high halves of qp)
                const v2f q0l = sp(qp[4*h+0].x), q0h = sp(qp[4*h+0].y);
                const v2f q1l = sp(qp[4*h+1].x), q1h = sp(qp[4*h+1].y);
                const v2f q2l = sp(qp[4*h+2].x), q2h = sp(qp[4*h+2].y);
                const v2f q3l = sp(qp[4*h+3].x), q3h = sp(qp[4*h+3].y);
                v2f ls0 = {0.f,0.f}, ls1 = {0.f,0.f};
                v2f oc00={0.f,0.f}, oc01={0.f,0.f}, oc02={0.f,0.f}, oc03={0.f,0.f};
                v2f oc10={0.f,0.f}, oc11={0.f,0.f}, oc12={0.f,0.f}, oc13={0.f,0.f};
                #pragma unroll
                for (int i = 0; i < NPAIR; ++i) {     // t = 0..67 (67 = zero-pad)
                    float4 ka = pKA[i], kb = pKB[i];
                    float4 va = pVA[i], vb = pVB[i];
                    v2f kx = *(const v2f*)&ka.x, ky = *(const v2f*)&ka.z;
                    v2f kz = *(const v2f*)&kb.x, kw = *(const v2f*)&kb.z;
                    v2f sc0 = q0l*kx + q1l*ky + q2l*kz + q3l*kw;   // row r0, {t0,t1}
                    v2f sc1 = q0h*kx + q1h*ky + q2h*kz + q3h*kw;   // row r1
                    v2f e0, e1;
                    e0.x = EXP2F(sc0.x);  e0.y = EXP2F(sc0.y);
                    e1.x = EXP2F(sc1.x);  e1.y = EXP2F(sc1.y);
                    ls0 += e0;  ls1 += e1;
                    v2f v0 = *(const v2f*)&va.x, v1 = *(const v2f*)&va.z;
                    v2f v2 = *(const v2f*)&vb.x, v3 = *(const v2f*)&vb.z;
                    oc00 += e0*v0; oc01 += e0*v1; oc02 += e0*v2; oc03 += e0*v3;
                    oc10 += e1*v0; oc11 += e1*v1; oc12 += e1*v2; oc13 += e1*v3;
                }
                float l0 = ls0.x + ls0.y - 1.0f;   // remove pad's exp2(0)=1
                float l1 = ls1.x + ls1.y - 1.0f;
                float i0 = RCPF(l0), i1 = RCPF(l1);
                os[4*h+0] = (v2f){(oc00.x+oc00.y)*i0, (oc10.x+oc10.y)*i1};
                os[4*h+1] = (v2f){(oc01.x+oc01.y)*i0, (oc11.x+oc11.y)*i1};
                os[4*h+2] = (v2f){(oc02.x+oc02.y)*i0, (oc12.x+oc12.y)*i1};
                os[4*h+3] = (v2f){(oc03.x+oc03.y)*i0, (oc13.x+oc13.y)*i1};
            }

            // attn_out + residual + LN1
            {
                const float* WA = aow + l*64;   // [8][8]
                const float* BA = aob + l*8;
                #pragma unroll
                for (int e = 0; e < E; ++e) {
                    v2f a = sp(BA[e]);
                    #pragma unroll
                    for (int e2 = 0; e2 < E; ++e2) a += os[e2] * sp(WA[e*8 + e2]);
                    xr[e] += a;
                }
            }
            ln8p(xr, g1 + l*E, b1 + l*E);

            // FF
            {
                const float* W1 = f1w + l*128;  // [16][8]
                const float* B1 = f1b + l*16;
                const float* W2 = f2w + l*128;  // [8][16]
                const float* B2 = f2b + l*8;
                v2f t1[FF];
                #pragma unroll
                for (int f = 0; f < FF; ++f) {
                    v2f a = sp(B1[f]);
                    #pragma unroll
                    for (int e = 0; e < E; ++e) a += xr[e] * sp(W1[f*8 + e]);
                    a.x = fmaxf(a.x, 0.f);
                    a.y = fmaxf(a.y, 0.f);
                    t1[f] = a;
                }
                #pragma unroll
                for (int e = 0; e < E; ++e) {
                    v2f a = sp(B2[e]);
                    #pragma unroll
                    for (int f = 0; f < FF; ++f) a += t1[f] * sp(W2[e*16 + f]);
                    xr[e] += a;
                }
            }
            ln8p(xr, g2 + l*E, b2 + l*E);
        }
        __syncthreads();   // protect K/V before next layer overwrites
    }

    if (active) {
        float* dst = xf + (size_t)n * KF + r0 * E;   // rows 2j,2j+1 contiguous
        *(float4*)(dst + 0) = make_float4(xr[0].x, xr[1].x, xr[2].x, xr[3].x);
        *(float4*)(dst + 4) = make_float4(xr[4].x, xr[5].x, xr[6].x, xr[7].x);
        if (!pad) {
            *(float4*)(dst + 8)  = make_float4(xr[0].y, xr[1].y, xr[2].y, xr[3].y);
            *(float4*)(dst + 12) = make_float4(xr[4].y, xr[5].y, xr[6].y, xr[7].y);
        }
    }
}

// wt[k][c] = ow[c][k]
__global__ void tr_kernel(const float* __restrict__ ow, float* __restrict__ wt)
{
    int i = blockIdx.x * 256 + threadIdx.x;
    if (i < OUTC * KF) {
        int c = i / KF, k = i - c * KF;
        wt[k * OUTC + c] = ow[i];
    }
}

// out = tanh(Xf[32768,536] @ Wt[536,128] + b)
__global__ __launch_bounds__(256, 4)
void out_kernel(const float* __restrict__ xf, const float* __restrict__ wt,
                const float* __restrict__ ob, float* __restrict__ out)
{
    __shared__ float Xs[32][68];
    const int lid = threadIdx.x;
    const int tx  = lid & 31;
    const int ty  = lid >> 5;
    const int n0  = blockIdx.x * 32;

    float acc[4][4] = {};

    #pragma unroll 1
    for (int kc = 0; kc < 9; ++kc) {
        const int kb = kc * 64;
        const int kw = (kc < 8) ? 64 : 24;
        __syncthreads();
        const int nvec = 32 * (kw >> 2);
        for (int i = lid; i < nvec; i += 256) {
            int r = i / (kw >> 2), kq = i - r * (kw >> 2);
            *(float4*)&Xs[r][kq*4] =
                *(const float4*)&xf[(size_t)(n0 + r) * KF + kb + kq*4];
        }
        __syncthreads();
        #pragma unroll 4
        for (int k = 0; k < kw; ++k) {
            float4 w4 = *(const float4*)&wt[(size_t)(kb + k) * OUTC + tx*4];
            #pragma unroll
            for (int i = 0; i < 4; ++i) {
                float x = Xs[ty*4 + i][k];
                acc[i][0] += x*w4.x; acc[i][1] += x*w4.y;
                acc[i][2] += x*w4.z; acc[i][3] += x*w4.w;
            }
        }
    }

    const float4 bb = *(const float4*)&ob[tx*4];
    #pragma unroll
    for (int i = 0; i < 4; ++i) {
        int r = n0 + ty*4 + i;
        float4 v;
        v.x = tanhf(acc[i][0] + bb.x);
        v.y = tanhf(acc[i][1] + bb.y);
        v.z = tanhf(acc[i][2] + bb.z);
        v.w = tanhf(acc[i][3] + bb.w);
        *(float4*)(out + (size_t)r * OUTC + tx*4) = v;
    }
}

extern "C" void kernel_launch(void* const* d_in, const int* in_sizes, int n_in,
                              void* d_out, int out_size, void* d_ws, size_t ws_size,
                              hipStream_t stream) {
    (void)in_sizes; (void)n_in; (void)out_size; (void)ws_size;
    const float* pose = (const float*)d_in[0];
    const float* ew   = (const float*)d_in[1];
    const float* eb   = (const float*)d_in[2];
    const float* ipw  = (const float*)d_in[3];
    const float* ipb  = (const float*)d_in[4];
    const float* aow  = (const float*)d_in[5];
    const float* aob  = (const float*)d_in[6];
    const float* f1w  = (const float*)d_in[7];
    const float* f1b  = (const float*)d_in[8];
    const float* f2w  = (const float*)d_in[9];
    const float* f2b  = (const float*)d_in[10];
    const float* g1   = (const float*)d_in[11];
    const float* b1   = (const float*)d_in[12];
    const float* g2   = (const float*)d_in[13];
    const float* b2   = (const float*)d_in[14];
    const float* ow   = (const float*)d_in[15];
    const float* ob   = (const float*)d_in[16];

    float* xf = (float*)d_ws;                               // 70.25 MB
    float* wt = xf + (size_t)NTOT * KF;                     // 268 KB

    const int grid1 = (NTOT + EPB - 1) / EPB;               // 4682
    enc_kernel<<<grid1, THREADS, 0, stream>>>(pose, ew, eb, ipw, ipb, aow, aob,
                                              f1w, f1b, f2w, f2b, g1, b1, g2, b2, xf);
    tr_kernel<<<(OUTC*KF + 255)/256, 256, 0, stream>>>(ow, wt);
    out_kernel<<<NTOT / 32, 256, 0, stream>>>(xf, wt, ob, (float*)d_out);
}